// Round 14
// baseline (164.783 us; speedup 1.0000x reference)
//
#include <hip/hip_runtime.h>
#include <math.h>

#define B_ 8
#define C_ 256
#define N_ 4096
#define K_ 1024
#define NH_ 8
#define HD_ 32

typedef __attribute__((ext_vector_type(8))) short short8;     // 8 x bf16 (4 VGPRs)
typedef __attribute__((ext_vector_type(8))) _Float16 half8;   // 8 x f16  (4 VGPRs)
typedef __attribute__((ext_vector_type(4))) _Float16 half4;   // 4 x f16  (2 VGPRs)
typedef __attribute__((ext_vector_type(4))) float f32x4;      // MFMA accumulator

// exp dispatch: fold log2e into Q scale and use raw v_exp_f32 when available
#if __has_builtin(__builtin_amdgcn_exp2f)
#define EXPX(x) __builtin_amdgcn_exp2f(x)
#define QSCALE (0.17677669529663688f * 1.4426950408889634f)
#else
#define EXPX(x) __expf(x)
#define QSCALE 0.17677669529663688f
#endif

// fp32 -> bf16 bits, round-to-nearest-even
__device__ __forceinline__ unsigned bfr(float x){
  unsigned u = __float_as_uint(x);
  return (u + 0x7FFFu + ((u >> 16) & 1u)) >> 16;
}
__device__ __forceinline__ unsigned pk2(float lo, float hi){   // bf16 pair [lo | hi<<16]
  return bfr(lo) | (bfr(hi) << 16);
}
__device__ __forceinline__ unsigned hpk(float a, float b){     // f16 pair
  _Float16 ha = (_Float16)a, hb = (_Float16)b;
  unsigned short ua = __builtin_bit_cast(unsigned short, ha);
  unsigned short ub = __builtin_bit_cast(unsigned short, hb);
  return (unsigned)ua | ((unsigned)ub << 16);
}
__device__ __forceinline__ half4 pk4rtz(float a, float b, float c, float d){ // 2x v_cvt_pkrtz
  auto lo = __builtin_amdgcn_cvt_pkrtz(a, b);
  auto hi = __builtin_amdgcn_cvt_pkrtz(c, d);
  uint2 u = make_uint2(__builtin_bit_cast(unsigned, lo), __builtin_bit_cast(unsigned, hi));
  return __builtin_bit_cast(half4, u);
}

// ---------------- Kernel 0: convert wq/wk/wv/wo fp32 -> f16 [4][256][256] ----------------
__global__ __launch_bounds__(256) void w2h_kernel(
    const float* __restrict__ wq, const float* __restrict__ wk,
    const float* __restrict__ wv, const float* __restrict__ wo,
    unsigned short* __restrict__ wh)
{
  const float* src = blockIdx.y==0 ? wq : blockIdx.y==1 ? wk : blockIdx.y==2 ? wv : wo;
  const int e = (blockIdx.x*256 + threadIdx.x)*8;
  float4 a = *(const float4*)(src + e);
  float4 b = *(const float4*)(src + e + 4);
  uint4 o;
  o.x = hpk(a.x, a.y); o.y = hpk(a.z, a.w);
  o.z = hpk(b.x, b.y); o.w = hpk(b.z, b.w);
  *(uint4*)(wh + (size_t)blockIdx.y*65536 + e) = o;
}

// ---------------- Kernel 1: importance + fused x->out copy (LDS-free streaming) ----------
// fp32 throughout (top-K selection must match fp32 reference ranking).
// Thread (p4=t&15, og=t>>4): 4 pixels (n0+4p4..+3, contiguous!) x 4 hidden outs.
// x read as contiguous float4 along N; the wave's 4 og-groups share the same 16 addresses
// (single 256B transaction). og==0 group also stores the x->out identity copy as float4.
// No LDS tile, no main-loop barriers; 1KB LDS for the final og-reduction only.
__global__ __launch_bounds__(256) void imp_kernel(
    const float* __restrict__ x, const float* __restrict__ bmap,
    const float* __restrict__ w1, const float* __restrict__ b1,
    const float* __restrict__ w2, const float* __restrict__ b2,
    float* __restrict__ imp_out, float* __restrict__ outx)
{
  __shared__ float red[4][64];
  const int t = threadIdx.x;
  const int b = blockIdx.x >> 6, tile = blockIdx.x & 63;
  const int n0 = tile * 64;
  const int p4 = t & 15, og = t >> 4;
  const float* xb = x + (size_t)b*C_*N_ + n0 + 4*p4;
  float* ox = outx + (size_t)b*C_*N_ + n0 + 4*p4;
  const float* wr0 = w1 + (size_t)(4*og+0)*C_;
  const float* wr1 = w1 + (size_t)(4*og+1)*C_;
  const float* wr2 = w1 + (size_t)(4*og+2)*C_;
  const float* wr3 = w1 + (size_t)(4*og+3)*C_;

  float acc[4][4];  // [pp][oo]
  #pragma unroll
  for (int pp=0;pp<4;pp++)
    #pragma unroll
    for (int oo=0;oo<4;oo++) acc[pp][oo] = 0.f;

  #pragma unroll 2
  for (int c = 0; c < 256; c += 4){
    float4 xv0 = *(const float4*)(xb + (size_t)(c+0)*N_);
    float4 xv1 = *(const float4*)(xb + (size_t)(c+1)*N_);
    float4 xv2 = *(const float4*)(xb + (size_t)(c+2)*N_);
    float4 xv3 = *(const float4*)(xb + (size_t)(c+3)*N_);
    float4 wv0 = *(const float4*)(wr0 + c);
    float4 wv1 = *(const float4*)(wr1 + c);
    float4 wv2 = *(const float4*)(wr2 + c);
    float4 wv3 = *(const float4*)(wr3 + c);
    if (og == 0){
      *(float4*)(ox + (size_t)(c+0)*N_) = xv0;
      *(float4*)(ox + (size_t)(c+1)*N_) = xv1;
      *(float4*)(ox + (size_t)(c+2)*N_) = xv2;
      *(float4*)(ox + (size_t)(c+3)*N_) = xv3;
    }
    const float xp0[4] = {xv0.x, xv0.y, xv0.z, xv0.w};
    const float xp1[4] = {xv1.x, xv1.y, xv1.z, xv1.w};
    const float xp2[4] = {xv2.x, xv2.y, xv2.z, xv2.w};
    const float xp3[4] = {xv3.x, xv3.y, xv3.z, xv3.w};
    const float4 wv[4] = {wv0, wv1, wv2, wv3};
    #pragma unroll
    for (int pp=0;pp<4;pp++)
      #pragma unroll
      for (int oo=0;oo<4;oo++)
        acc[pp][oo] += xp0[pp]*wv[oo].x + xp1[pp]*wv[oo].y
                     + xp2[pp]*wv[oo].z + xp3[pp]*wv[oo].w;
  }
  // epilogue: GELU + w2 dot, reduce over the 64 hidden outs
  float part[4] = {0.f,0.f,0.f,0.f};
  #pragma unroll
  for (int oo=0;oo<4;oo++){
    const int o = 4*og + oo;
    const float b1o = b1[o], w2o = w2[o];
    #pragma unroll
    for (int pp=0;pp<4;pp++){
      float a = acc[pp][oo] + b1o;
      float g = 0.5f*a*(1.f + erff(a*0.70710678118654752f));  // exact GELU
      part[pp] += w2o*g;
    }
  }
  #pragma unroll
  for (int pp=0;pp<4;pp++){
    part[pp] += __shfl_xor(part[pp], 16);   // sum over the wave's 4 og-subgroups
    part[pp] += __shfl_xor(part[pp], 32);
  }
  const int w = t >> 6;
  if ((t & 63) < 16){
    #pragma unroll
    for (int pp=0;pp<4;pp++) red[w][4*(t&15)+pp] = part[pp];
  }
  __syncthreads();
  if (t < 64){
    float s = red[0][t]+red[1][t]+red[2][t]+red[3][t] + b2[0];
    float sig = 1.f/(1.f+expf(-s));
    imp_out[(size_t)b*N_ + n0 + t] = sig + 0.5f*bmap[(size_t)b*N_ + n0 + t];
  }
}

// ---------------- Kernel 2: exact top-K: bitonic sort + threshold scan-compact ----------------
__global__ __launch_bounds__(1024) void topk_kernel(const float* __restrict__ imp, int* __restrict__ tidx)
{
  __shared__ unsigned long long s[4096];
  __shared__ int ws2[16];
  const int b = blockIdx.x, t = threadIdx.x;
  const float* ib = imp + (size_t)b*N_;
  for (int m = t; m < N_; m += 1024){
    unsigned u = __float_as_uint(ib[m]);
    u = (u & 0x80000000u) ? ~u : (u | 0x80000000u);        // order-preserving bits
    s[m] = ((unsigned long long)u << 32) | (unsigned)(~m); // tie -> lower index wins
  }
  for (int k = 2; k <= 4096; k <<= 1){
    for (int j = k >> 1; j > 0; j >>= 1){
      __syncthreads();
      #pragma unroll 2
      for (int m = t; m < 2048; m += 1024){
        int i = 2*m - (m & (j-1));
        int l = i + j;
        unsigned long long a = s[i], c = s[l];
        if ((a > c) == ((i & k) == 0)){ s[i] = c; s[l] = a; }
      }
    }
  }
  __syncthreads();
  // threshold = 1024-th largest key (keys all distinct: index embedded)
  const unsigned long long thr = s[3072];
  // ordered compaction: thread t owns m = 4t..4t+3; recompute keys; block scan
  int sel[4]; int cnt = 0;
  #pragma unroll
  for (int u2 = 0; u2 < 4; u2++){
    const int m = 4*t + u2;
    unsigned u = __float_as_uint(ib[m]);
    u = (u & 0x80000000u) ? ~u : (u | 0x80000000u);
    unsigned long long key = ((unsigned long long)u << 32) | (unsigned)(~m);
    sel[u2] = (key >= thr) ? 1 : 0;
    cnt += sel[u2];
  }
  int incl = cnt;                         // inclusive wave scan
  #pragma unroll
  for (int d2 = 1; d2 < 64; d2 <<= 1){
    int v2 = __shfl_up(incl, d2);
    if ((t & 63) >= d2) incl += v2;
  }
  if ((t & 63) == 63) ws2[t >> 6] = incl;
  __syncthreads();
  int base = 0;
  const int wv2 = t >> 6;
  #pragma unroll
  for (int ww = 0; ww < 16; ww++) if (ww < wv2) base += ws2[ww];
  int pos = base + incl - cnt;            // exclusive prefix
  #pragma unroll
  for (int u2 = 0; u2 < 4; u2++){
    if (sel[u2]) tidx[(size_t)b*K_ + pos++] = 4*t + u2;
  }
}

// ---------------- Kernel 3: fused gather + Q/K/V projections via f16 MFMA ----------------
// Q is pre-scaled by QSCALE. V^T stored f16 with keys PERMUTED within each 32-token block:
//   rel key k (0..31) -> pos 8*((k&15)>>2) + 4*((k>>4)&1) + (k&3)
__global__ __launch_bounds__(512) void qkv_kernel(
    const float* __restrict__ x, const int* __restrict__ tidx,
    const unsigned short* __restrict__ wh,
    const float* __restrict__ bq, const float* __restrict__ bk, const float* __restrict__ bv,
    float* __restrict__ xsp, unsigned short* __restrict__ qbf,
    unsigned short* __restrict__ kbf, unsigned short* __restrict__ vtb)
{
  __shared__ unsigned short xsb[16][256];   // f16 bits, swizzled 16B granules
  const int t = threadIdx.x;
  const int kt = blockIdx.x, b = blockIdx.y;
  const int tok0 = kt*16;
  { // gather: thread t -> token i = t&15, granule jg = t>>4 (8 channels)
    const int i = t & 15, jg = t >> 4;
    const int n = tidx[(size_t)b*K_ + tok0 + i];
    const float* xb = x + (size_t)b*C_*N_ + n;
    float v[8];
    #pragma unroll
    for (int u = 0; u < 8; u++) v[u] = xb[(size_t)(jg*8+u)*N_];
    float* xr = xsp + ((size_t)b*K_ + tok0 + i)*C_ + jg*8;
    *(float4*)(xr)     = make_float4(v[0],v[1],v[2],v[3]);
    *(float4*)(xr + 4) = make_float4(v[4],v[5],v[6],v[7]);
    uint4 pw;
    pw.x = hpk(v[0],v[1]); pw.y = hpk(v[2],v[3]);
    pw.z = hpk(v[4],v[5]); pw.w = hpk(v[6],v[7]);
    *(uint4*)((char*)&xsb[0][0] + i*512 + ((jg ^ (i&7))*16)) = pw;
  }
  __syncthreads();

  const int lane = t & 63, w = t >> 6;
  const int g = lane >> 4, c = lane & 15;

  f32x4 acc[3][2];
  #pragma unroll
  for (int s=0;s<3;s++)
    #pragma unroll
    for (int j=0;j<2;j++) acc[s][j] = (f32x4){0.f,0.f,0.f,0.f};

  #pragma unroll 1
  for (int ks = 0; ks < 8; ks++){
    half8 Xf = *(const half8*)((const char*)&xsb[0][0] + c*512 + (((4*ks+g) ^ (c&7))*16));
    half8 Wf[3][2];
    #pragma unroll
    for (int s=0;s<3;s++)
      #pragma unroll
      for (int j=0;j<2;j++)
        Wf[s][j] = *(const half8*)(wh + (size_t)s*65536 + (32*w + 16*j + c)*C_ + ks*32 + 8*g);
    acc[0][0] = __builtin_amdgcn_mfma_f32_16x16x32_f16(Wf[0][0], Xf, acc[0][0], 0,0,0);
    acc[0][1] = __builtin_amdgcn_mfma_f32_16x16x32_f16(Wf[0][1], Xf, acc[0][1], 0,0,0);
    acc[1][0] = __builtin_amdgcn_mfma_f32_16x16x32_f16(Wf[1][0], Xf, acc[1][0], 0,0,0);
    acc[1][1] = __builtin_amdgcn_mfma_f32_16x16x32_f16(Wf[1][1], Xf, acc[1][1], 0,0,0);
    acc[2][0] = __builtin_amdgcn_mfma_f32_16x16x32_f16(Xf, Wf[2][0], acc[2][0], 0,0,0);
    acc[2][1] = __builtin_amdgcn_mfma_f32_16x16x32_f16(Xf, Wf[2][1], acc[2][1], 0,0,0);
  }

  const int bh = b*NH_ + w;   // head = wave index
  #pragma unroll
  for (int s=0;s<2;s++){
    const float* bias = s ? bk : bq;
    const float sc = s ? 1.f : QSCALE;
    unsigned short* dstb = s ? kbf : qbf;
    #pragma unroll
    for (int j=0;j<2;j++){
      f32x4 a = acc[s][j];
      float4 bb = *(const float4*)(bias + w*32 + 16*j + 4*g);
      unsigned lo = pk2((a[0]+bb.x)*sc, (a[1]+bb.y)*sc);
      unsigned hi = pk2((a[2]+bb.z)*sc, (a[3]+bb.w)*sc);
      unsigned short* dst = dstb + ((size_t)bh*K_ + tok0 + c)*HD_ + 16*j + 4*g;
      *(uint2*)dst = make_uint2(lo, hi);
    }
  }
  // V^T scatter, f16, key-permuted: lane holds tokens tok0+4g+{0..3} = rel 16*half+4g+r
  const int base32 = tok0 & ~31;
  const int half   = (tok0 >> 4) & 1;
  #pragma unroll
  for (int j=0;j<2;j++){
    f32x4 a = acc[2][j];
    const float bvv = bv[w*32 + 16*j + c];
    unsigned lo = hpk(a[0]+bvv, a[1]+bvv);
    unsigned hi = hpk(a[2]+bvv, a[3]+bvv);
    unsigned short* dst = vtb + ((size_t)bh*HD_ + 16*j + c)*K_ + base32 + 8*g + 4*half;
    *(uint2*)dst = make_uint2(lo, hi);
  }
}

// ---------------- Kernel 4: MFMA flash attention, depth-2 register pipeline ----------------
// L computed on the matrix pipe: mfma(ONES, P) gives every lane Sum_k P[k][q].
// Grid flat = h + 8*(qt + 8*b). 8 waves = (sp,qq): split-K 2-way, merge by plain addition.
__global__ __launch_bounds__(512) void attn_kernel(
    const unsigned short* __restrict__ qbf, const unsigned short* __restrict__ kbf,
    const unsigned short* __restrict__ vtb, unsigned short* __restrict__ ob)
{
  __shared__ float po[4][64][19];   // [qq][lane][ot(16) | L0 | L1]; stride 19 -> <=2-way
  const int tid = threadIdx.x;
  const int t = tid & 63, w = tid >> 6;
  const int sp = w >> 2, qq = w & 3;
  const int flat = blockIdx.x;
  const int h = flat & 7;
  const int rest = flat >> 3;      // 0..63
  const int qt = rest & 7;
  const int b = rest >> 3;         // 0..7
  const int g = t >> 4, c = t & 15;
  const int bh = b*NH_ + h;
  const int q0 = qt*128 + qq*32;   // 32 q-rows per wave

  short8 Qf0 = *(const short8*)(qbf + ((size_t)bh*K_ + q0 + c)*HD_ + g*8);
  short8 Qf1 = *(const short8*)(qbf + ((size_t)bh*K_ + q0 + 16 + c)*HD_ + g*8);

  const int kbeg = sp*512;
  const unsigned short* kp  = kbf + (size_t)bh*K_*HD_ + (size_t)(kbeg + c)*HD_ + g*8;
  const unsigned short* vp0 = vtb + ((size_t)bh*HD_ + c)*K_ + kbeg + g*8;
  const unsigned short* vp1 = vp0 + (size_t)16*K_;

  const half4 ONES = {(_Float16)1.f, (_Float16)1.f, (_Float16)1.f, (_Float16)1.f};
  f32x4 ot00 = {0.f,0.f,0.f,0.f}, ot01 = {0.f,0.f,0.f,0.f};  // qi=0: dv 0..15, 16..31
  f32x4 ot10 = {0.f,0.f,0.f,0.f}, ot11 = {0.f,0.f,0.f,0.f};  // qi=1
  f32x4 otL0 = {0.f,0.f,0.f,0.f}, otL1 = {0.f,0.f,0.f,0.f};  // L accumulators

#define ATTN_STEP(K0c,K1c,V0c,V1c) do {                                           \
    f32x4 z = {0.f,0.f,0.f,0.f};                                                  \
    __builtin_amdgcn_s_setprio(1);                                                \
    f32x4 s00 = __builtin_amdgcn_mfma_f32_16x16x32_bf16(K0c, Qf0, z, 0, 0, 0);    \
    f32x4 s01 = __builtin_amdgcn_mfma_f32_16x16x32_bf16(K1c, Qf0, z, 0, 0, 0);    \
    f32x4 s10 = __builtin_amdgcn_mfma_f32_16x16x32_bf16(K0c, Qf1, z, 0, 0, 0);    \
    f32x4 s11 = __builtin_amdgcn_mfma_f32_16x16x32_bf16(K1c, Qf1, z, 0, 0, 0);    \
    __builtin_amdgcn_s_setprio(0);                                                \
    float p00[4], p01[4], p10[4], p11[4];                                         \
    _Pragma("unroll")                                                             \
    for (int r=0;r<4;r++){                                                        \
      p00[r] = EXPX(s00[r]); p01[r] = EXPX(s01[r]);                               \
      p10[r] = EXPX(s10[r]); p11[r] = EXPX(s11[r]);                               \
    }                                                                             \
    half4 P00 = pk4rtz(p00[0], p00[1], p00[2], p00[3]);                           \
    half4 P01 = pk4rtz(p01[0], p01[1], p01[2], p01[3]);                           \
    half4 P10 = pk4rtz(p10[0], p10[1], p10[2], p10[3]);                           \
    half4 P11 = pk4rtz(p11[0], p11[1], p11[2], p11[3]);                           \
    half4 A0lo = __builtin_shufflevector(V0c, V0c, 0, 1, 2, 3);                   \
    half4 A0hi = __builtin_shufflevector(V0c, V0c, 4, 5, 6, 7);                   \
    half4 A1lo = __builtin_shufflevector(V1c, V1c, 0, 1, 2, 3);                   \
    half4 A1hi = __builtin_shufflevector(V1c, V1c, 4, 5, 6, 7);                   \
    __builtin_amdgcn_s_setprio(1);                                                \
    ot00 = __builtin_amdgcn_mfma_f32_16x16x16f16(A0lo, P00, ot00, 0, 0, 0);       \
    ot00 = __builtin_amdgcn_mfma_f32_16x16x16f16(A0hi, P01, ot00, 0, 0, 0);       \
    ot01 = __builtin_amdgcn_mfma_f32_16x16x16f16(A1lo, P00, ot01, 0, 0, 0);       \
    ot01 = __builtin_amdgcn_mfma_f32_16x16x16f16(A1hi, P01, ot01, 0, 0, 0);       \
    ot10 = __builtin_amdgcn_mfma_f32_16x16x16f16(A0lo, P10, ot10, 0, 0, 0);       \
    ot10 = __builtin_amdgcn_mfma_f32_16x16x16f16(A0hi, P11, ot10, 0, 0, 0);       \
    ot11 = __builtin_amdgcn_mfma_f32_16x16x16f16(A1lo, P10, ot11, 0, 0, 0);       \
    ot11 = __builtin_amdgcn_mfma_f32_16x16x16f16(A1hi, P11, ot11, 0, 0, 0);       \
    otL0 = __builtin_amdgcn_mfma_f32_16x16x16f16(ONES, P00, otL0, 0, 0, 0);       \
    otL0 = __builtin_amdgcn_mfma_f32_16x16x16f16(ONES, P01, otL0, 0, 0, 0);       \
    otL1 = __builtin_amdgcn_mfma_f32_16x16x16f16(ONES, P10, otL1, 0, 0, 0);       \
    otL1 = __builtin_amdgcn_mfma_f32_16x16x16f16(ONES, P11, otL1, 0, 0, 0);       \
    __builtin_amdgcn_s_setprio(0);                                                \
  } while(0)

  // depth-2 register pipeline; prefetches past the region land in allocated workspace
  short8 K0a = *(const short8*)(kp);
  short8 K1a = *(const short8*)(kp + 16*HD_);
  half8  V0a = *(const half8*)(vp0);
  half8  V1a = *(const half8*)(vp1);
  kp += 32*HD_; vp0 += 32; vp1 += 32;
  short8 K0b = *(const short8*)(kp);
  short8 K1b = *(const short8*)(kp + 16*HD_);
  half8  V0b = *(const half8*)(vp0);
  half8  V1b = *(const half8*)(vp1);

  for (int it = 0; it < 16; it += 2){
    kp += 32*HD_; vp0 += 32; vp1 += 32;
    short8 K0n = *(const short8*)(kp);
    short8 K1n = *(const short8*)(kp + 16*HD_);
    half8  V0n = *(const half8*)(vp0);
    half8  V1n = *(const half8*)(vp1);
    ATTN_STEP(K0a, K1a, V0a, V1a);
    K0a = K0n; K1a = K1n; V0a = V0n; V1a = V1n;
    kp += 32*HD_; vp0 += 32; vp1 += 32;
    short8 K0m = *(const short8*)(kp);
    short8 K1m = *(const short8*)(kp + 16*HD_);
    half8  V0m = *(const half8*)(vp0);
    half8  V1m = *(const half8*)(vp1);
    ATTN_STEP(K0b, K1b, V0b, V1b);
    K0b = K0m; K1b = K1m; V0b = V0m; V1b = V1m;
  }
#undef ATTN_STEP

  if (sp == 1){
    float* d = po[qq][t];
    d[0]=ot00[0]; d[1]=ot00[1]; d[2]=ot00[2];  d[3]=ot00[3];
    d[4]=ot01[0]; d[5]=ot01[1]; d[6]=ot01[2];  d[7]=ot01[3];
    d[8]=ot10[0]; d[9]=ot10[1]; d[10]=ot10[2]; d[11]=ot10[3];
    d[12]=ot11[0];d[13]=ot11[1];d[14]=ot11[2]; d[15]=ot11[3];
    d[16]=otL0[0]; d[17]=otL1[0];
  }
  __syncthreads();
  if (sp == 0){
    const float* d = po[qq][t];
    ot00[0]+=d[0]; ot00[1]+=d[1]; ot00[2]+=d[2];  ot00[3]+=d[3];
    ot01[0]+=d[4]; ot01[1]+=d[5]; ot01[2]+=d[6];  ot01[3]+=d[7];
    ot10[0]+=d[8]; ot10[1]+=d[9]; ot10[2]+=d[10]; ot10[3]+=d[11];
    ot11[0]+=d[12];ot11[1]+=d[13];ot11[2]+=d[14]; ot11[3]+=d[15];
    const float L0 = otL0[0] + d[16];
    const float L1 = otL1[0] + d[17];
    const float i0 = 1.f / L0, i1 = 1.f / L1;
    unsigned short* o0 = ob + ((size_t)b*K_ + q0 + c)*C_ + h*HD_;
    unsigned short* o1 = ob + ((size_t)b*K_ + q0 + 16 + c)*C_ + h*HD_;
    *(uint2*)(o0 + 4*g)      = make_uint2(hpk(ot00[0]*i0, ot00[1]*i0), hpk(ot00[2]*i0, ot00[3]*i0));
    *(uint2*)(o0 + 16 + 4*g) = make_uint2(hpk(ot01[0]*i0, ot01[1]*i0), hpk(ot01[2]*i0, ot01[3]*i0));
    *(uint2*)(o1 + 4*g)      = make_uint2(hpk(ot10[0]*i1, ot10[1]*i1), hpk(ot10[2]*i1, ot10[3]*i1));
    *(uint2*)(o1 + 16 + 4*g) = make_uint2(hpk(ot11[0]*i1, ot11[1]*i1), hpk(ot11[2]*i1, ot11[3]*i1));
  }
}

// ---------------- Kernel 5: out-proj (f16 MFMA) + residual + LayerNorm + scatter ----------------
// 32-token tiles -> grid (32,8) = 256 blocks (one per CU).
__global__ __launch_bounds__(512) void out_kernel(
    const unsigned short* __restrict__ ob, const float* __restrict__ xsp,
    const int* __restrict__ tidx, const unsigned short* __restrict__ woh, const float* __restrict__ bo,
    const float* __restrict__ lng, const float* __restrict__ lnb,
    float* __restrict__ out)
{
  __shared__ float red1[8][32], red2[8][32];
  __shared__ float mus[32], rss[32];
  __shared__ int nn[32];
  const int t = threadIdx.x;
  const int kt = blockIdx.x, b = blockIdx.y;
  const int tok0 = kt*32;
  const int lane = t & 63, w = t >> 6;
  const int g = lane >> 4, c = lane & 15;

  if (t < 32) nn[t] = tidx[(size_t)b*K_ + tok0 + t];

  f32x4 acc[2][2];
  #pragma unroll
  for (int j=0;j<2;j++)
    #pragma unroll
    for (int tt=0;tt<2;tt++) acc[j][tt] = (f32x4){0.f,0.f,0.f,0.f};

  const unsigned short* ob0 = ob + ((size_t)b*K_ + tok0)*C_;
  const unsigned short* wr0 = woh + (32*w + c)*C_;

  #pragma unroll 1
  for (int ks = 0; ks < 8; ks++){
    half8 Wf0 = *(const half8*)(wr0 + ks*32 + 8*g);
    half8 Wf1 = *(const half8*)(wr0 + 16*C_ + ks*32 + 8*g);
    #pragma unroll
    for (int tt=0;tt<2;tt++){
      half8 Of = *(const half8*)(ob0 + (size_t)(16*tt + c)*C_ + ks*32 + 8*g);
      acc[0][tt] = __builtin_amdgcn_mfma_f32_16x16x32_f16(Wf0, Of, acc[0][tt], 0,0,0);
      acc[1][tt] = __builtin_amdgcn_mfma_f32_16x16x32_f16(Wf1, Of, acc[1][tt], 0,0,0);
    }
  }

  // bias + residual (fp32)
  float4 bb[2];
  #pragma unroll
  for (int j=0;j<2;j++) bb[j] = *(const float4*)(bo + 32*w + 16*j + 4*g);
  #pragma unroll
  for (int tt=0;tt<2;tt++){
    const float* xr = xsp + ((size_t)b*K_ + tok0 + 16*tt + c)*C_ + 32*w + 4*g;
    #pragma unroll
    for (int j=0;j<2;j++){
      float4 xv = *(const float4*)(xr + 16*j);
      acc[j][tt][0] += bb[j].x + xv.x;
      acc[j][tt][1] += bb[j].y + xv.y;
      acc[j][tt][2] += bb[j].z + xv.z;
      acc[j][tt][3] += bb[j].w + xv.w;
    }
  }

  // LN partials: per token sum over this wave's 32 oc; g-groups share the token
  #pragma unroll
  for (int tt=0;tt<2;tt++){
    float s1 = 0.f, s2 = 0.f;
    #pragma unroll
    for (int j=0;j<2;j++)
      #pragma unroll
      for (int r=0;r<4;r++){ float y = acc[j][tt][r]; s1 += y; s2 += y*y; }
    s1 += __shfl_xor(s1, 16); s2 += __shfl_xor(s2, 16);
    s1 += __shfl_xor(s1, 32); s2 += __shfl_xor(s2, 32);
    if (g == 0){ red1[w][16*tt + c] = s1; red2[w][16*tt + c] = s2; }
  }
  __syncthreads();
  if (t < 32){
    float a = 0.f, q2 = 0.f;
    #pragma unroll
    for (int ww=0;ww<8;ww++){ a += red1[ww][t]; q2 += red2[ww][t]; }
    float mu = a*(1.f/256.f);
    float var = q2*(1.f/256.f) - mu*mu;
    mus[t] = mu;
    rss[t] = rsqrtf(var + 1e-5f);
  }
  __syncthreads();

  // scale/shift + scatter
  float4 gv[2], bv2[2];
  #pragma unroll
  for (int j=0;j<2;j++){
    gv[j]  = *(const float4*)(lng + 32*w + 16*j + 4*g);
    bv2[j] = *(const float4*)(lnb + 32*w + 16*j + 4*g);
  }
  float* outb = out + (size_t)b*C_*N_;
  #pragma unroll
  for (int tt=0;tt<2;tt++){
    const int tok = 16*tt + c;
    const float mu = mus[tok], rs = rss[tok];
    const int n = nn[tok];
    #pragma unroll
    for (int j=0;j<2;j++){
      const int oc0 = 32*w + 16*j + 4*g;
      const float* gvp = (const float*)&gv[j];
      const float* bvp = (const float*)&bv2[j];
      #pragma unroll
      for (int r=0;r<4;r++)
        outb[(size_t)(oc0 + r)*N_ + n] = (acc[j][tt][r]-mu)*rs*gvp[r] + bvp[r];
    }
  }
}

extern "C" void kernel_launch(void* const* d_in, const int* in_sizes, int n_in,
                              void* d_out, int out_size, void* d_ws, size_t ws_size,
                              hipStream_t stream)
{
  const float* x    = (const float*)d_in[0];
  const float* bmap = (const float*)d_in[1];
  const float* w1   = (const float*)d_in[2];
  const float* b1   = (const float*)d_in[3];
  const float* w2   = (const float*)d_in[4];
  const float* b2   = (const float*)d_in[5];
  const float* wq   = (const float*)d_in[6];
  const float* bq   = (const float*)d_in[7];
  const float* wk   = (const float*)d_in[8];
  const float* bk   = (const float*)d_in[9];
  const float* wv   = (const float*)d_in[10];
  const float* bv   = (const float*)d_in[11];
  const float* wo   = (const float*)d_in[12];
  const float* bo   = (const float*)d_in[13];
  const float* lng  = (const float*)d_in[14];
  const float* lnb  = (const float*)d_in[15];

  float* out = (float*)d_out;
  float* imp_out = out + (size_t)B_*C_*N_;   // importance is output #2, concatenated

  char* wsb = (char*)d_ws;
  int*   tidx = (int*)wsb;                                // 64 KB slot
  float* xsp  = (float*)(wsb + 65536);                    // [B,K,C] fp32, 8 MB
  unsigned short* ob16 = (unsigned short*)(xsp + (size_t)B_*K_*C_); // [B,K,C] f16, 4 MB (8 MB slot)
  unsigned short* qbf = ob16 + 2*(size_t)B_*K_*C_;        // [B,H,K,32] bf16, 4 MB
  unsigned short* kbf = qbf + (size_t)B_*NH_*K_*HD_;      // [B,H,K,32] bf16, 4 MB
  unsigned short* vtb = kbf + (size_t)B_*NH_*K_*HD_;      // [B,H,32,K] f16 key-permuted, 4 MB
  unsigned short* wh  = vtb + (size_t)B_*NH_*K_*HD_;      // [4][256][256] f16, 512 KB

  w2h_kernel <<<dim3(32, 4),    dim3(256),  0, stream>>>(wq, wk, wv, wo, wh);
  imp_kernel <<<dim3(512),      dim3(256),  0, stream>>>(x, bmap, w1, b1, w2, b2, imp_out, out);
  topk_kernel<<<dim3(8),        dim3(1024), 0, stream>>>(imp_out, tidx);
  qkv_kernel <<<dim3(64, 8),    dim3(512),  0, stream>>>(x, tidx, wh, bq, bk, bv, xsp, qbf, kbf, vtb);
  attn_kernel<<<dim3(512),      dim3(512),  0, stream>>>(qbf, kbf, vtb, ob16);
  out_kernel <<<dim3(32, 8),    dim3(512),  0, stream>>>(ob16, xsp, tidx, wh + 3*65536, bo, lng, lnb, out);
}

// Round 15
// 162.768 us; speedup vs baseline: 1.0124x; 1.0124x over previous
//
#include <hip/hip_runtime.h>
#include <math.h>

#define B_ 8
#define C_ 256
#define N_ 4096
#define K_ 1024
#define NH_ 8
#define HD_ 32

typedef __attribute__((ext_vector_type(8))) short short8;     // 8 x bf16 (4 VGPRs)
typedef __attribute__((ext_vector_type(8))) _Float16 half8;   // 8 x f16  (4 VGPRs)
typedef __attribute__((ext_vector_type(4))) _Float16 half4;   // 4 x f16  (2 VGPRs)
typedef __attribute__((ext_vector_type(4))) float f32x4;      // MFMA accumulator

// exp dispatch: fold log2e into Q scale and use raw v_exp_f32 when available
#if __has_builtin(__builtin_amdgcn_exp2f)
#define EXPX(x) __builtin_amdgcn_exp2f(x)
#define QSCALE (0.17677669529663688f * 1.4426950408889634f)
#else
#define EXPX(x) __expf(x)
#define QSCALE 0.17677669529663688f
#endif

// fp32 -> bf16 bits, round-to-nearest-even
__device__ __forceinline__ unsigned bfr(float x){
  unsigned u = __float_as_uint(x);
  return (u + 0x7FFFu + ((u >> 16) & 1u)) >> 16;
}
__device__ __forceinline__ unsigned pk2(float lo, float hi){   // bf16 pair [lo | hi<<16]
  return bfr(lo) | (bfr(hi) << 16);
}
__device__ __forceinline__ unsigned hpk(float a, float b){     // f16 pair
  _Float16 ha = (_Float16)a, hb = (_Float16)b;
  unsigned short ua = __builtin_bit_cast(unsigned short, ha);
  unsigned short ub = __builtin_bit_cast(unsigned short, hb);
  return (unsigned)ua | ((unsigned)ub << 16);
}
__device__ __forceinline__ half4 pk4rtz(float a, float b, float c, float d){ // 2x v_cvt_pkrtz
  auto lo = __builtin_amdgcn_cvt_pkrtz(a, b);
  auto hi = __builtin_amdgcn_cvt_pkrtz(c, d);
  uint2 u = make_uint2(__builtin_bit_cast(unsigned, lo), __builtin_bit_cast(unsigned, hi));
  return __builtin_bit_cast(half4, u);
}

// ---------------- Kernel 0: convert wq/wk/wv/wo fp32 -> f16 [4][256][256] ----------------
__global__ __launch_bounds__(256) void w2h_kernel(
    const float* __restrict__ wq, const float* __restrict__ wk,
    const float* __restrict__ wv, const float* __restrict__ wo,
    unsigned short* __restrict__ wh)
{
  const float* src = blockIdx.y==0 ? wq : blockIdx.y==1 ? wk : blockIdx.y==2 ? wv : wo;
  const int e = (blockIdx.x*256 + threadIdx.x)*8;
  float4 a = *(const float4*)(src + e);
  float4 b = *(const float4*)(src + e + 4);
  uint4 o;
  o.x = hpk(a.x, a.y); o.y = hpk(a.z, a.w);
  o.z = hpk(b.x, b.y); o.w = hpk(b.z, b.w);
  *(uint4*)(wh + (size_t)blockIdx.y*65536 + e) = o;
}

// ---------------- Kernel 1: importance + fused x->out copy ----------------
// fp32 throughout (top-K selection must match fp32 reference ranking).
// 128 threads: thread (pg=t&15, og=t>>4) computes 4 pixels x 8 hidden outs.
// Same 8 ds_read_b128 per step now feed 256 FMAs (LDS:VALU = 96:512 per wave-step),
// relieving the LDS pipe that capped the 4x4 retile (R13: 384 LDS-cyc per 256 wall).
// Gather phase also writes the x->out identity copy (replaces the 32MB D2D memcpy).
__global__ __launch_bounds__(128) void imp_kernel(
    const float* __restrict__ x, const float* __restrict__ bmap,
    const float* __restrict__ w1, const float* __restrict__ b1,
    const float* __restrict__ w2, const float* __restrict__ b2,
    float* __restrict__ imp_out, float* __restrict__ outx)
{
  __shared__ float xs[64][256];   // 64 pixels x 256 channels, granule-swizzled
  const int t = threadIdx.x;
  const int b = blockIdx.x >> 6, tile = blockIdx.x & 63;
  const int n0 = tile * 64;
  { // gather: thread t -> pixel i = t&63, channel half cg = t>>6 (128 ch as 32 granules)
    const int i = t & 63, cg = t >> 6;
    const float* xb = x + (size_t)b*C_*N_ + n0 + i;
    float* ox = outx + (size_t)b*C_*N_ + n0 + i;
    const int ib = (i & 15) ^ (i >> 2);
    #pragma unroll 4
    for (int cc = 0; cc < 32; cc++){
      const int c0 = cg*128 + cc*4;
      float4 v;
      v.x = xb[(size_t)(c0+0)*N_];
      v.y = xb[(size_t)(c0+1)*N_];
      v.z = xb[(size_t)(c0+2)*N_];
      v.w = xb[(size_t)(c0+3)*N_];
      *(float4*)&xs[i][4*((cg*32+cc) ^ ib)] = v;
      ox[(size_t)(c0+0)*N_] = v.x;
      ox[(size_t)(c0+1)*N_] = v.y;
      ox[(size_t)(c0+2)*N_] = v.z;
      ox[(size_t)(c0+3)*N_] = v.w;
    }
  }
  __syncthreads();
  const int pg = t & 15, og = t >> 4;   // pixels 4pg..+3, hidden outs 8og..+7
  float acc[4][8];  // [pp][oo]
  #pragma unroll
  for (int pp=0;pp<4;pp++)
    #pragma unroll
    for (int oo=0;oo<8;oo++) acc[pp][oo] = 0.f;
  int pb[4];
  #pragma unroll
  for (int pp=0;pp<4;pp++){ int p = 4*pg+pp; pb[pp] = (p&15)^(p>>2); }
  #pragma unroll 2
  for (int c8 = 0; c8 < 256; c8 += 8){
    const int G = c8 >> 2;
    float4 xa[4], xc[4];
    #pragma unroll
    for (int pp=0;pp<4;pp++){
      xa[pp] = *(const float4*)&xs[4*pg+pp][4*( G    ^ pb[pp])];
      xc[pp] = *(const float4*)&xs[4*pg+pp][4*((G+1) ^ pb[pp])];
    }
    #pragma unroll
    for (int oo=0;oo<8;oo++){
      const float* wr = w1 + (size_t)(8*og+oo)*C_ + c8;
      float4 wa = *(const float4*)wr;
      float4 wb = *(const float4*)(wr+4);
      #pragma unroll
      for (int pp=0;pp<4;pp++)
        acc[pp][oo] += xa[pp].x*wa.x + xa[pp].y*wa.y + xa[pp].z*wa.z + xa[pp].w*wa.w
                     + xc[pp].x*wb.x + xc[pp].y*wb.y + xc[pp].z*wb.z + xc[pp].w*wb.w;
    }
  }
  // epilogue: GELU + w2 dot, reduce over the 64 hidden outs
  float part[4] = {0.f,0.f,0.f,0.f};
  #pragma unroll
  for (int oo=0;oo<8;oo++){
    const int o = 8*og + oo;
    const float b1o = b1[o], w2o = w2[o];
    #pragma unroll
    for (int pp=0;pp<4;pp++){
      float a = acc[pp][oo] + b1o;
      float g = 0.5f*a*(1.f + erff(a*0.70710678118654752f));  // exact GELU
      part[pp] += w2o*g;
    }
  }
  #pragma unroll
  for (int pp=0;pp<4;pp++){
    part[pp] += __shfl_xor(part[pp], 16);   // sum over the wave's 4 og-subgroups
    part[pp] += __shfl_xor(part[pp], 32);
  }
  __syncthreads();
  float* red = &xs[0][0];   // reuse LDS after all reads done
  const int w = t >> 6;
  if ((t & 63) < 16){
    #pragma unroll
    for (int pp=0;pp<4;pp++) red[w*64 + 4*(t&15)+pp] = part[pp];
  }
  __syncthreads();
  if (t < 64){
    float s = red[t] + red[64+t] + b2[0];
    float sig = 1.f/(1.f+expf(-s));
    imp_out[(size_t)b*N_ + n0 + t] = sig + 0.5f*bmap[(size_t)b*N_ + n0 + t];
  }
}

// ---------------- Kernel 2: exact top-K: bitonic sort + threshold scan-compact ----------------
__global__ __launch_bounds__(1024) void topk_kernel(const float* __restrict__ imp, int* __restrict__ tidx)
{
  __shared__ unsigned long long s[4096];
  __shared__ int ws2[16];
  const int b = blockIdx.x, t = threadIdx.x;
  const float* ib = imp + (size_t)b*N_;
  for (int m = t; m < N_; m += 1024){
    unsigned u = __float_as_uint(ib[m]);
    u = (u & 0x80000000u) ? ~u : (u | 0x80000000u);        // order-preserving bits
    s[m] = ((unsigned long long)u << 32) | (unsigned)(~m); // tie -> lower index wins
  }
  for (int k = 2; k <= 4096; k <<= 1){
    for (int j = k >> 1; j > 0; j >>= 1){
      __syncthreads();
      #pragma unroll 2
      for (int m = t; m < 2048; m += 1024){
        int i = 2*m - (m & (j-1));
        int l = i + j;
        unsigned long long a = s[i], c = s[l];
        if ((a > c) == ((i & k) == 0)){ s[i] = c; s[l] = a; }
      }
    }
  }
  __syncthreads();
  // threshold = 1024-th largest key (keys all distinct: index embedded)
  const unsigned long long thr = s[3072];
  // ordered compaction: thread t owns m = 4t..4t+3; recompute keys; block scan
  int sel[4]; int cnt = 0;
  #pragma unroll
  for (int u2 = 0; u2 < 4; u2++){
    const int m = 4*t + u2;
    unsigned u = __float_as_uint(ib[m]);
    u = (u & 0x80000000u) ? ~u : (u | 0x80000000u);
    unsigned long long key = ((unsigned long long)u << 32) | (unsigned)(~m);
    sel[u2] = (key >= thr) ? 1 : 0;
    cnt += sel[u2];
  }
  int incl = cnt;                         // inclusive wave scan
  #pragma unroll
  for (int d2 = 1; d2 < 64; d2 <<= 1){
    int v2 = __shfl_up(incl, d2);
    if ((t & 63) >= d2) incl += v2;
  }
  if ((t & 63) == 63) ws2[t >> 6] = incl;
  __syncthreads();
  int base = 0;
  const int wv2 = t >> 6;
  #pragma unroll
  for (int ww = 0; ww < 16; ww++) if (ww < wv2) base += ws2[ww];
  int pos = base + incl - cnt;            // exclusive prefix
  #pragma unroll
  for (int u2 = 0; u2 < 4; u2++){
    if (sel[u2]) tidx[(size_t)b*K_ + pos++] = 4*t + u2;
  }
}

// ---------------- Kernel 3: fused gather + Q/K/V projections via f16 MFMA ----------------
// Q is pre-scaled by QSCALE. V^T stored f16 with keys PERMUTED within each 32-token block:
//   rel key k (0..31) -> pos 8*((k&15)>>2) + 4*((k>>4)&1) + (k&3)
__global__ __launch_bounds__(512) void qkv_kernel(
    const float* __restrict__ x, const int* __restrict__ tidx,
    const unsigned short* __restrict__ wh,
    const float* __restrict__ bq, const float* __restrict__ bk, const float* __restrict__ bv,
    float* __restrict__ xsp, unsigned short* __restrict__ qbf,
    unsigned short* __restrict__ kbf, unsigned short* __restrict__ vtb)
{
  __shared__ unsigned short xsb[16][256];   // f16 bits, swizzled 16B granules
  const int t = threadIdx.x;
  const int kt = blockIdx.x, b = blockIdx.y;
  const int tok0 = kt*16;
  { // gather: thread t -> token i = t&15, granule jg = t>>4 (8 channels)
    const int i = t & 15, jg = t >> 4;
    const int n = tidx[(size_t)b*K_ + tok0 + i];
    const float* xb = x + (size_t)b*C_*N_ + n;
    float v[8];
    #pragma unroll
    for (int u = 0; u < 8; u++) v[u] = xb[(size_t)(jg*8+u)*N_];
    float* xr = xsp + ((size_t)b*K_ + tok0 + i)*C_ + jg*8;
    *(float4*)(xr)     = make_float4(v[0],v[1],v[2],v[3]);
    *(float4*)(xr + 4) = make_float4(v[4],v[5],v[6],v[7]);
    uint4 pw;
    pw.x = hpk(v[0],v[1]); pw.y = hpk(v[2],v[3]);
    pw.z = hpk(v[4],v[5]); pw.w = hpk(v[6],v[7]);
    *(uint4*)((char*)&xsb[0][0] + i*512 + ((jg ^ (i&7))*16)) = pw;
  }
  __syncthreads();

  const int lane = t & 63, w = t >> 6;
  const int g = lane >> 4, c = lane & 15;

  f32x4 acc[3][2];
  #pragma unroll
  for (int s=0;s<3;s++)
    #pragma unroll
    for (int j=0;j<2;j++) acc[s][j] = (f32x4){0.f,0.f,0.f,0.f};

  #pragma unroll 1
  for (int ks = 0; ks < 8; ks++){
    half8 Xf = *(const half8*)((const char*)&xsb[0][0] + c*512 + (((4*ks+g) ^ (c&7))*16));
    half8 Wf[3][2];
    #pragma unroll
    for (int s=0;s<3;s++)
      #pragma unroll
      for (int j=0;j<2;j++)
        Wf[s][j] = *(const half8*)(wh + (size_t)s*65536 + (32*w + 16*j + c)*C_ + ks*32 + 8*g);
    acc[0][0] = __builtin_amdgcn_mfma_f32_16x16x32_f16(Wf[0][0], Xf, acc[0][0], 0,0,0);
    acc[0][1] = __builtin_amdgcn_mfma_f32_16x16x32_f16(Wf[0][1], Xf, acc[0][1], 0,0,0);
    acc[1][0] = __builtin_amdgcn_mfma_f32_16x16x32_f16(Wf[1][0], Xf, acc[1][0], 0,0,0);
    acc[1][1] = __builtin_amdgcn_mfma_f32_16x16x32_f16(Wf[1][1], Xf, acc[1][1], 0,0,0);
    acc[2][0] = __builtin_amdgcn_mfma_f32_16x16x32_f16(Xf, Wf[2][0], acc[2][0], 0,0,0);
    acc[2][1] = __builtin_amdgcn_mfma_f32_16x16x32_f16(Xf, Wf[2][1], acc[2][1], 0,0,0);
  }

  const int bh = b*NH_ + w;   // head = wave index
  #pragma unroll
  for (int s=0;s<2;s++){
    const float* bias = s ? bk : bq;
    const float sc = s ? 1.f : QSCALE;
    unsigned short* dstb = s ? kbf : qbf;
    #pragma unroll
    for (int j=0;j<2;j++){
      f32x4 a = acc[s][j];
      float4 bb = *(const float4*)(bias + w*32 + 16*j + 4*g);
      unsigned lo = pk2((a[0]+bb.x)*sc, (a[1]+bb.y)*sc);
      unsigned hi = pk2((a[2]+bb.z)*sc, (a[3]+bb.w)*sc);
      unsigned short* dst = dstb + ((size_t)bh*K_ + tok0 + c)*HD_ + 16*j + 4*g;
      *(uint2*)dst = make_uint2(lo, hi);
    }
  }
  // V^T scatter, f16, key-permuted: lane holds tokens tok0+4g+{0..3} = rel 16*half+4g+r
  const int base32 = tok0 & ~31;
  const int half   = (tok0 >> 4) & 1;
  #pragma unroll
  for (int j=0;j<2;j++){
    f32x4 a = acc[2][j];
    const float bvv = bv[w*32 + 16*j + c];
    unsigned lo = hpk(a[0]+bvv, a[1]+bvv);
    unsigned hi = hpk(a[2]+bvv, a[3]+bvv);
    unsigned short* dst = vtb + ((size_t)bh*HD_ + 16*j + c)*K_ + base32 + 8*g + 4*half;
    *(uint2*)dst = make_uint2(lo, hi);
  }
}

// ---------------- Kernel 4: MFMA flash attention, depth-2 register pipeline ----------------
// L computed on the matrix pipe: mfma(ONES, P) gives every lane Sum_k P[k][q].
// Grid flat = h + 8*(qt + 8*b). 8 waves = (sp,qq): split-K 2-way, merge by plain addition.
__global__ __launch_bounds__(512) void attn_kernel(
    const unsigned short* __restrict__ qbf, const unsigned short* __restrict__ kbf,
    const unsigned short* __restrict__ vtb, unsigned short* __restrict__ ob)
{
  __shared__ float po[4][64][19];   // [qq][lane][ot(16) | L0 | L1]; stride 19 -> <=2-way
  const int tid = threadIdx.x;
  const int t = tid & 63, w = tid >> 6;
  const int sp = w >> 2, qq = w & 3;
  const int flat = blockIdx.x;
  const int h = flat & 7;
  const int rest = flat >> 3;      // 0..63
  const int qt = rest & 7;
  const int b = rest >> 3;         // 0..7
  const int g = t >> 4, c = t & 15;
  const int bh = b*NH_ + h;
  const int q0 = qt*128 + qq*32;   // 32 q-rows per wave

  short8 Qf0 = *(const short8*)(qbf + ((size_t)bh*K_ + q0 + c)*HD_ + g*8);
  short8 Qf1 = *(const short8*)(qbf + ((size_t)bh*K_ + q0 + 16 + c)*HD_ + g*8);

  const int kbeg = sp*512;
  const unsigned short* kp  = kbf + (size_t)bh*K_*HD_ + (size_t)(kbeg + c)*HD_ + g*8;
  const unsigned short* vp0 = vtb + ((size_t)bh*HD_ + c)*K_ + kbeg + g*8;
  const unsigned short* vp1 = vp0 + (size_t)16*K_;

  const half4 ONES = {(_Float16)1.f, (_Float16)1.f, (_Float16)1.f, (_Float16)1.f};
  f32x4 ot00 = {0.f,0.f,0.f,0.f}, ot01 = {0.f,0.f,0.f,0.f};  // qi=0: dv 0..15, 16..31
  f32x4 ot10 = {0.f,0.f,0.f,0.f}, ot11 = {0.f,0.f,0.f,0.f};  // qi=1
  f32x4 otL0 = {0.f,0.f,0.f,0.f}, otL1 = {0.f,0.f,0.f,0.f};  // L accumulators

#define ATTN_STEP(K0c,K1c,V0c,V1c) do {                                           \
    f32x4 z = {0.f,0.f,0.f,0.f};                                                  \
    __builtin_amdgcn_s_setprio(1);                                                \
    f32x4 s00 = __builtin_amdgcn_mfma_f32_16x16x32_bf16(K0c, Qf0, z, 0, 0, 0);    \
    f32x4 s01 = __builtin_amdgcn_mfma_f32_16x16x32_bf16(K1c, Qf0, z, 0, 0, 0);    \
    f32x4 s10 = __builtin_amdgcn_mfma_f32_16x16x32_bf16(K0c, Qf1, z, 0, 0, 0);    \
    f32x4 s11 = __builtin_amdgcn_mfma_f32_16x16x32_bf16(K1c, Qf1, z, 0, 0, 0);    \
    __builtin_amdgcn_s_setprio(0);                                                \
    float p00[4], p01[4], p10[4], p11[4];                                         \
    _Pragma("unroll")                                                             \
    for (int r=0;r<4;r++){                                                        \
      p00[r] = EXPX(s00[r]); p01[r] = EXPX(s01[r]);                               \
      p10[r] = EXPX(s10[r]); p11[r] = EXPX(s11[r]);                               \
    }                                                                             \
    half4 P00 = pk4rtz(p00[0], p00[1], p00[2], p00[3]);                           \
    half4 P01 = pk4rtz(p01[0], p01[1], p01[2], p01[3]);                           \
    half4 P10 = pk4rtz(p10[0], p10[1], p10[2], p10[3]);                           \
    half4 P11 = pk4rtz(p11[0], p11[1], p11[2], p11[3]);                           \
    half4 A0lo = __builtin_shufflevector(V0c, V0c, 0, 1, 2, 3);                   \
    half4 A0hi = __builtin_shufflevector(V0c, V0c, 4, 5, 6, 7);                   \
    half4 A1lo = __builtin_shufflevector(V1c, V1c, 0, 1, 2, 3);                   \
    half4 A1hi = __builtin_shufflevector(V1c, V1c, 4, 5, 6, 7);                   \
    __builtin_amdgcn_s_setprio(1);                                                \
    ot00 = __builtin_amdgcn_mfma_f32_16x16x16f16(A0lo, P00, ot00, 0, 0, 0);       \
    ot00 = __builtin_amdgcn_mfma_f32_16x16x16f16(A0hi, P01, ot00, 0, 0, 0);       \
    ot01 = __builtin_amdgcn_mfma_f32_16x16x16f16(A1lo, P00, ot01, 0, 0, 0);       \
    ot01 = __builtin_amdgcn_mfma_f32_16x16x16f16(A1hi, P01, ot01, 0, 0, 0);       \
    ot10 = __builtin_amdgcn_mfma_f32_16x16x16f16(A0lo, P10, ot10, 0, 0, 0);       \
    ot10 = __builtin_amdgcn_mfma_f32_16x16x16f16(A0hi, P11, ot10, 0, 0, 0);       \
    ot11 = __builtin_amdgcn_mfma_f32_16x16x16f16(A1lo, P10, ot11, 0, 0, 0);       \
    ot11 = __builtin_amdgcn_mfma_f32_16x16x16f16(A1hi, P11, ot11, 0, 0, 0);       \
    otL0 = __builtin_amdgcn_mfma_f32_16x16x16f16(ONES, P00, otL0, 0, 0, 0);       \
    otL0 = __builtin_amdgcn_mfma_f32_16x16x16f16(ONES, P01, otL0, 0, 0, 0);       \
    otL1 = __builtin_amdgcn_mfma_f32_16x16x16f16(ONES, P10, otL1, 0, 0, 0);       \
    otL1 = __builtin_amdgcn_mfma_f32_16x16x16f16(ONES, P11, otL1, 0, 0, 0);       \
    __builtin_amdgcn_s_setprio(0);                                                \
  } while(0)

  // depth-2 register pipeline; prefetches past the region land in allocated workspace
  short8 K0a = *(const short8*)(kp);
  short8 K1a = *(const short8*)(kp + 16*HD_);
  half8  V0a = *(const half8*)(vp0);
  half8  V1a = *(const half8*)(vp1);
  kp += 32*HD_; vp0 += 32; vp1 += 32;
  short8 K0b = *(const short8*)(kp);
  short8 K1b = *(const short8*)(kp + 16*HD_);
  half8  V0b = *(const half8*)(vp0);
  half8  V1b = *(const half8*)(vp1);

  for (int it = 0; it < 16; it += 2){
    kp += 32*HD_; vp0 += 32; vp1 += 32;
    short8 K0n = *(const short8*)(kp);
    short8 K1n = *(const short8*)(kp + 16*HD_);
    half8  V0n = *(const half8*)(vp0);
    half8  V1n = *(const half8*)(vp1);
    ATTN_STEP(K0a, K1a, V0a, V1a);
    K0a = K0n; K1a = K1n; V0a = V0n; V1a = V1n;
    kp += 32*HD_; vp0 += 32; vp1 += 32;
    short8 K0m = *(const short8*)(kp);
    short8 K1m = *(const short8*)(kp + 16*HD_);
    half8  V0m = *(const half8*)(vp0);
    half8  V1m = *(const half8*)(vp1);
    ATTN_STEP(K0b, K1b, V0b, V1b);
    K0b = K0m; K1b = K1m; V0b = V0m; V1b = V1m;
  }
#undef ATTN_STEP

  if (sp == 1){
    float* d = po[qq][t];
    d[0]=ot00[0]; d[1]=ot00[1]; d[2]=ot00[2];  d[3]=ot00[3];
    d[4]=ot01[0]; d[5]=ot01[1]; d[6]=ot01[2];  d[7]=ot01[3];
    d[8]=ot10[0]; d[9]=ot10[1]; d[10]=ot10[2]; d[11]=ot10[3];
    d[12]=ot11[0];d[13]=ot11[1];d[14]=ot11[2]; d[15]=ot11[3];
    d[16]=otL0[0]; d[17]=otL1[0];
  }
  __syncthreads();
  if (sp == 0){
    const float* d = po[qq][t];
    ot00[0]+=d[0]; ot00[1]+=d[1]; ot00[2]+=d[2];  ot00[3]+=d[3];
    ot01[0]+=d[4]; ot01[1]+=d[5]; ot01[2]+=d[6];  ot01[3]+=d[7];
    ot10[0]+=d[8]; ot10[1]+=d[9]; ot10[2]+=d[10]; ot10[3]+=d[11];
    ot11[0]+=d[12];ot11[1]+=d[13];ot11[2]+=d[14]; ot11[3]+=d[15];
    const float L0 = otL0[0] + d[16];
    const float L1 = otL1[0] + d[17];
    const float i0 = 1.f / L0, i1 = 1.f / L1;
    unsigned short* o0 = ob + ((size_t)b*K_ + q0 + c)*C_ + h*HD_;
    unsigned short* o1 = ob + ((size_t)b*K_ + q0 + 16 + c)*C_ + h*HD_;
    *(uint2*)(o0 + 4*g)      = make_uint2(hpk(ot00[0]*i0, ot00[1]*i0), hpk(ot00[2]*i0, ot00[3]*i0));
    *(uint2*)(o0 + 16 + 4*g) = make_uint2(hpk(ot01[0]*i0, ot01[1]*i0), hpk(ot01[2]*i0, ot01[3]*i0));
    *(uint2*)(o1 + 4*g)      = make_uint2(hpk(ot10[0]*i1, ot10[1]*i1), hpk(ot10[2]*i1, ot10[3]*i1));
    *(uint2*)(o1 + 16 + 4*g) = make_uint2(hpk(ot11[0]*i1, ot11[1]*i1), hpk(ot11[2]*i1, ot11[3]*i1));
  }
}

// ---------------- Kernel 5: out-proj (f16 MFMA) + residual + LayerNorm + scatter ----------------
// 32-token tiles -> grid (32,8) = 256 blocks (one per CU).
__global__ __launch_bounds__(512) void out_kernel(
    const unsigned short* __restrict__ ob, const float* __restrict__ xsp,
    const int* __restrict__ tidx, const unsigned short* __restrict__ woh, const float* __restrict__ bo,
    const float* __restrict__ lng, const float* __restrict__ lnb,
    float* __restrict__ out)
{
  __shared__ float red1[8][32], red2[8][32];
  __shared__ float mus[32], rss[32];
  __shared__ int nn[32];
  const int t = threadIdx.x;
  const int kt = blockIdx.x, b = blockIdx.y;
  const int tok0 = kt*32;
  const int lane = t & 63, w = t >> 6;
  const int g = lane >> 4, c = lane & 15;

  if (t < 32) nn[t] = tidx[(size_t)b*K_ + tok0 + t];

  f32x4 acc[2][2];
  #pragma unroll
  for (int j=0;j<2;j++)
    #pragma unroll
    for (int tt=0;tt<2;tt++) acc[j][tt] = (f32x4){0.f,0.f,0.f,0.f};

  const unsigned short* ob0 = ob + ((size_t)b*K_ + tok0)*C_;
  const unsigned short* wr0 = woh + (32*w + c)*C_;

  #pragma unroll 1
  for (int ks = 0; ks < 8; ks++){
    half8 Wf0 = *(const half8*)(wr0 + ks*32 + 8*g);
    half8 Wf1 = *(const half8*)(wr0 + 16*C_ + ks*32 + 8*g);
    #pragma unroll
    for (int tt=0;tt<2;tt++){
      half8 Of = *(const half8*)(ob0 + (size_t)(16*tt + c)*C_ + ks*32 + 8*g);
      acc[0][tt] = __builtin_amdgcn_mfma_f32_16x16x32_f16(Wf0, Of, acc[0][tt], 0,0,0);
      acc[1][tt] = __builtin_amdgcn_mfma_f32_16x16x32_f16(Wf1, Of, acc[1][tt], 0,0,0);
    }
  }

  // bias + residual (fp32)
  float4 bb[2];
  #pragma unroll
  for (int j=0;j<2;j++) bb[j] = *(const float4*)(bo + 32*w + 16*j + 4*g);
  #pragma unroll
  for (int tt=0;tt<2;tt++){
    const float* xr = xsp + ((size_t)b*K_ + tok0 + 16*tt + c)*C_ + 32*w + 4*g;
    #pragma unroll
    for (int j=0;j<2;j++){
      float4 xv = *(const float4*)(xr + 16*j);
      acc[j][tt][0] += bb[j].x + xv.x;
      acc[j][tt][1] += bb[j].y + xv.y;
      acc[j][tt][2] += bb[j].z + xv.z;
      acc[j][tt][3] += bb[j].w + xv.w;
    }
  }

  // LN partials: per token sum over this wave's 32 oc; g-groups share the token
  #pragma unroll
  for (int tt=0;tt<2;tt++){
    float s1 = 0.f, s2 = 0.f;
    #pragma unroll
    for (int j=0;j<2;j++)
      #pragma unroll
      for (int r=0;r<4;r++){ float y = acc[j][tt][r]; s1 += y; s2 += y*y; }
    s1 += __shfl_xor(s1, 16); s2 += __shfl_xor(s2, 16);
    s1 += __shfl_xor(s1, 32); s2 += __shfl_xor(s2, 32);
    if (g == 0){ red1[w][16*tt + c] = s1; red2[w][16*tt + c] = s2; }
  }
  __syncthreads();
  if (t < 32){
    float a = 0.f, q2 = 0.f;
    #pragma unroll
    for (int ww=0;ww<8;ww++){ a += red1[ww][t]; q2 += red2[ww][t]; }
    float mu = a*(1.f/256.f);
    float var = q2*(1.f/256.f) - mu*mu;
    mus[t] = mu;
    rss[t] = rsqrtf(var + 1e-5f);
  }
  __syncthreads();

  // scale/shift + scatter
  float4 gv[2], bv2[2];
  #pragma unroll
  for (int j=0;j<2;j++){
    gv[j]  = *(const float4*)(lng + 32*w + 16*j + 4*g);
    bv2[j] = *(const float4*)(lnb + 32*w + 16*j + 4*g);
  }
  float* outb = out + (size_t)b*C_*N_;
  #pragma unroll
  for (int tt=0;tt<2;tt++){
    const int tok = 16*tt + c;
    const float mu = mus[tok], rs = rss[tok];
    const int n = nn[tok];
    #pragma unroll
    for (int j=0;j<2;j++){
      const int oc0 = 32*w + 16*j + 4*g;
      const float* gvp = (const float*)&gv[j];
      const float* bvp = (const float*)&bv2[j];
      #pragma unroll
      for (int r=0;r<4;r++)
        outb[(size_t)(oc0 + r)*N_ + n] = (acc[j][tt][r]-mu)*rs*gvp[r] + bvp[r];
    }
  }
}

extern "C" void kernel_launch(void* const* d_in, const int* in_sizes, int n_in,
                              void* d_out, int out_size, void* d_ws, size_t ws_size,
                              hipStream_t stream)
{
  const float* x    = (const float*)d_in[0];
  const float* bmap = (const float*)d_in[1];
  const float* w1   = (const float*)d_in[2];
  const float* b1   = (const float*)d_in[3];
  const float* w2   = (const float*)d_in[4];
  const float* b2   = (const float*)d_in[5];
  const float* wq   = (const float*)d_in[6];
  const float* bq   = (const float*)d_in[7];
  const float* wk   = (const float*)d_in[8];
  const float* bk   = (const float*)d_in[9];
  const float* wv   = (const float*)d_in[10];
  const float* bv   = (const float*)d_in[11];
  const float* wo   = (const float*)d_in[12];
  const float* bo   = (const float*)d_in[13];
  const float* lng  = (const float*)d_in[14];
  const float* lnb  = (const float*)d_in[15];

  float* out = (float*)d_out;
  float* imp_out = out + (size_t)B_*C_*N_;   // importance is output #2, concatenated

  char* wsb = (char*)d_ws;
  int*   tidx = (int*)wsb;                                // 64 KB slot
  float* xsp  = (float*)(wsb + 65536);                    // [B,K,C] fp32, 8 MB
  unsigned short* ob16 = (unsigned short*)(xsp + (size_t)B_*K_*C_); // [B,K,C] f16, 4 MB (8 MB slot)
  unsigned short* qbf = ob16 + 2*(size_t)B_*K_*C_;        // [B,H,K,32] bf16, 4 MB
  unsigned short* kbf = qbf + (size_t)B_*NH_*K_*HD_;      // [B,H,K,32] bf16, 4 MB
  unsigned short* vtb = kbf + (size_t)B_*NH_*K_*HD_;      // [B,H,32,K] f16 key-permuted, 4 MB
  unsigned short* wh  = vtb + (size_t)B_*NH_*K_*HD_;      // [4][256][256] f16, 512 KB

  w2h_kernel <<<dim3(32, 4),    dim3(256),  0, stream>>>(wq, wk, wv, wo, wh);
  imp_kernel <<<dim3(512),      dim3(128),  0, stream>>>(x, bmap, w1, b1, w2, b2, imp_out, out);
  topk_kernel<<<dim3(8),        dim3(1024), 0, stream>>>(imp_out, tidx);
  qkv_kernel <<<dim3(64, 8),    dim3(512),  0, stream>>>(x, tidx, wh, bq, bk, bv, xsp, qbf, kbf, vtb);
  attn_kernel<<<dim3(512),      dim3(512),  0, stream>>>(qbf, kbf, vtb, ob16);
  out_kernel <<<dim3(32, 8),    dim3(512),  0, stream>>>(ob16, xsp, tidx, wh + 3*65536, bo, lng, lnb, out);
}

// Round 16
// 147.577 us; speedup vs baseline: 1.1166x; 1.1029x over previous
//
#include <hip/hip_runtime.h>
#include <math.h>

#define B_ 8
#define C_ 256
#define N_ 4096
#define K_ 1024
#define NH_ 8
#define HD_ 32

typedef __attribute__((ext_vector_type(8))) short short8;     // 8 x bf16 (4 VGPRs)
typedef __attribute__((ext_vector_type(8))) _Float16 half8;   // 8 x f16  (4 VGPRs)
typedef __attribute__((ext_vector_type(4))) _Float16 half4;   // 4 x f16  (2 VGPRs)
typedef __attribute__((ext_vector_type(4))) float f32x4;      // MFMA accumulator

// exp dispatch: fold log2e into Q scale and use raw v_exp_f32 when available
#if __has_builtin(__builtin_amdgcn_exp2f)
#define EXPX(x) __builtin_amdgcn_exp2f(x)
#define QSCALE (0.17677669529663688f * 1.4426950408889634f)
#else
#define EXPX(x) __expf(x)
#define QSCALE 0.17677669529663688f
#endif

// fp32 -> bf16 bits, round-to-nearest-even
__device__ __forceinline__ unsigned bfr(float x){
  unsigned u = __float_as_uint(x);
  return (u + 0x7FFFu + ((u >> 16) & 1u)) >> 16;
}
__device__ __forceinline__ unsigned pk2(float lo, float hi){   // bf16 pair [lo | hi<<16]
  return bfr(lo) | (bfr(hi) << 16);
}
__device__ __forceinline__ unsigned hpk(float a, float b){     // f16 pair
  _Float16 ha = (_Float16)a, hb = (_Float16)b;
  unsigned short ua = __builtin_bit_cast(unsigned short, ha);
  unsigned short ub = __builtin_bit_cast(unsigned short, hb);
  return (unsigned)ua | ((unsigned)ub << 16);
}
__device__ __forceinline__ half4 pk4rtz(float a, float b, float c, float d){ // 2x v_cvt_pkrtz
  auto lo = __builtin_amdgcn_cvt_pkrtz(a, b);
  auto hi = __builtin_amdgcn_cvt_pkrtz(c, d);
  uint2 u = make_uint2(__builtin_bit_cast(unsigned, lo), __builtin_bit_cast(unsigned, hi));
  return __builtin_bit_cast(half4, u);
}

// ---------------- Kernel 0: convert wq/wk/wv/wo fp32 -> f16 [4][256][256] ----------------
__global__ __launch_bounds__(256) void w2h_kernel(
    const float* __restrict__ wq, const float* __restrict__ wk,
    const float* __restrict__ wv, const float* __restrict__ wo,
    unsigned short* __restrict__ wh)
{
  const float* src = blockIdx.y==0 ? wq : blockIdx.y==1 ? wk : blockIdx.y==2 ? wv : wo;
  const int e = (blockIdx.x*256 + threadIdx.x)*8;
  float4 a = *(const float4*)(src + e);
  float4 b = *(const float4*)(src + e + 4);
  uint4 o;
  o.x = hpk(a.x, a.y); o.y = hpk(a.z, a.w);
  o.z = hpk(b.x, b.y); o.w = hpk(b.z, b.w);
  *(uint4*)(wh + (size_t)blockIdx.y*65536 + e) = o;
}

// ---------------- Kernel 1: importance + fused x->out copy (2-phase 32KB LDS tile) --------
// fp32 throughout, accumulation order identical to the proven R13 kernel (bit-identical
// outputs). Channel dim processed in two 128-ch halves through a 32KB LDS tile ->
// 5 blocks/CU instead of 2 (occupancy 2 -> 5 waves/SIMD), which is what R13 lacked.
// Thread (pg=t&15, og=t>>4): 4 pixels x 4 hidden outs. Gather also writes x->out copy.
__global__ __launch_bounds__(256) void imp_kernel(
    const float* __restrict__ x, const float* __restrict__ bmap,
    const float* __restrict__ w1, const float* __restrict__ b1,
    const float* __restrict__ w2, const float* __restrict__ b2,
    float* __restrict__ imp_out, float* __restrict__ outx)
{
  __shared__ float xs[64][128];   // 32KB: 64 pixels x 128 channels (one half), swizzled
  const int t = threadIdx.x;
  const int b = blockIdx.x >> 6, tile = blockIdx.x & 63;
  const int n0 = tile * 64;
  const int pg = t & 15, og = t >> 4;   // pixels 4pg..+3, hidden outs 4og..+3
  const int i = t & 63, cg = t >> 6;    // gather: pixel i, channel group cg*32..+31
  const int ib = (i & 15) ^ (i >> 2);
  const float* xb = x + (size_t)b*C_*N_ + n0 + i;
  float* ox = outx + (size_t)b*C_*N_ + n0 + i;

  float acc[4][4];  // [pp][oo]
  #pragma unroll
  for (int pp=0;pp<4;pp++)
    #pragma unroll
    for (int oo=0;oo<4;oo++) acc[pp][oo] = 0.f;
  int pb[4];
  #pragma unroll
  for (int pp=0;pp<4;pp++){ int p = 4*pg+pp; pb[pp] = (p&15)^(p>>2); }

  #pragma unroll 1
  for (int half = 0; half < 2; half++){
    // gather this half: 8 granules of 4 channels per thread + x->out copy
    #pragma unroll
    for (int cc = 0; cc < 8; cc++){
      const int c0 = half*128 + cg*32 + cc*4;
      float4 v;
      v.x = xb[(size_t)(c0+0)*N_];
      v.y = xb[(size_t)(c0+1)*N_];
      v.z = xb[(size_t)(c0+2)*N_];
      v.w = xb[(size_t)(c0+3)*N_];
      const int lg = cg*8 + cc;            // local granule 0..31
      *(float4*)&xs[i][4*(lg ^ ib)] = v;   // ib<16, lg<32 -> index <32, in-row
      ox[(size_t)(c0+0)*N_] = v.x;
      ox[(size_t)(c0+1)*N_] = v.y;
      ox[(size_t)(c0+2)*N_] = v.z;
      ox[(size_t)(c0+3)*N_] = v.w;
    }
    __syncthreads();
    const float* w1h = w1 + half*128;
    #pragma unroll 2
    for (int c8 = 0; c8 < 128; c8 += 8){
      const int G = c8 >> 2;
      float4 xa[4], xc[4];
      #pragma unroll
      for (int pp=0;pp<4;pp++){
        xa[pp] = *(const float4*)&xs[4*pg+pp][4*( G    ^ pb[pp])];
        xc[pp] = *(const float4*)&xs[4*pg+pp][4*((G+1) ^ pb[pp])];
      }
      float4 wa[4], wb[4];
      #pragma unroll
      for (int oo=0;oo<4;oo++){
        const float* wr = w1h + (size_t)(4*og+oo)*C_ + c8;
        wa[oo] = *(const float4*)wr;
        wb[oo] = *(const float4*)(wr+4);
      }
      #pragma unroll
      for (int pp=0;pp<4;pp++)
        #pragma unroll
        for (int oo=0;oo<4;oo++)
          acc[pp][oo] += xa[pp].x*wa[oo].x + xa[pp].y*wa[oo].y + xa[pp].z*wa[oo].z + xa[pp].w*wa[oo].w
                       + xc[pp].x*wb[oo].x + xc[pp].y*wb[oo].y + xc[pp].z*wb[oo].z + xc[pp].w*wb[oo].w;
    }
    __syncthreads();
  }
  // epilogue: GELU + w2 dot, reduce over the 64 hidden outs
  float part[4] = {0.f,0.f,0.f,0.f};
  #pragma unroll
  for (int oo=0;oo<4;oo++){
    const int o = 4*og + oo;
    const float b1o = b1[o], w2o = w2[o];
    #pragma unroll
    for (int pp=0;pp<4;pp++){
      float a = acc[pp][oo] + b1o;
      float g = 0.5f*a*(1.f + erff(a*0.70710678118654752f));  // exact GELU
      part[pp] += w2o*g;
    }
  }
  #pragma unroll
  for (int pp=0;pp<4;pp++){
    part[pp] += __shfl_xor(part[pp], 16);   // sum over wave-local og
    part[pp] += __shfl_xor(part[pp], 32);
  }
  float* red = &xs[0][0];   // reuse LDS after all reads done (post-barrier)
  const int w = t >> 6;
  if ((t & 63) < 16){
    #pragma unroll
    for (int pp=0;pp<4;pp++) red[w*64 + 4*(t&15)+pp] = part[pp];
  }
  __syncthreads();
  if (t < 64){
    float s = red[t]+red[64+t]+red[128+t]+red[192+t] + b2[0];
    float sig = 1.f/(1.f+expf(-s));
    imp_out[(size_t)b*N_ + n0 + t] = sig + 0.5f*bmap[(size_t)b*N_ + n0 + t];
  }
}

// ---------------- Kernel 2: exact top-K: bitonic sort + threshold scan-compact ----------------
__global__ __launch_bounds__(1024) void topk_kernel(const float* __restrict__ imp, int* __restrict__ tidx)
{
  __shared__ unsigned long long s[4096];
  __shared__ int ws2[16];
  const int b = blockIdx.x, t = threadIdx.x;
  const float* ib = imp + (size_t)b*N_;
  for (int m = t; m < N_; m += 1024){
    unsigned u = __float_as_uint(ib[m]);
    u = (u & 0x80000000u) ? ~u : (u | 0x80000000u);        // order-preserving bits
    s[m] = ((unsigned long long)u << 32) | (unsigned)(~m); // tie -> lower index wins
  }
  for (int k = 2; k <= 4096; k <<= 1){
    for (int j = k >> 1; j > 0; j >>= 1){
      __syncthreads();
      #pragma unroll 2
      for (int m = t; m < 2048; m += 1024){
        int i = 2*m - (m & (j-1));
        int l = i + j;
        unsigned long long a = s[i], c = s[l];
        if ((a > c) == ((i & k) == 0)){ s[i] = c; s[l] = a; }
      }
    }
  }
  __syncthreads();
  // threshold = 1024-th largest key (keys all distinct: index embedded)
  const unsigned long long thr = s[3072];
  // ordered compaction: thread t owns m = 4t..4t+3; recompute keys; block scan
  int sel[4]; int cnt = 0;
  #pragma unroll
  for (int u2 = 0; u2 < 4; u2++){
    const int m = 4*t + u2;
    unsigned u = __float_as_uint(ib[m]);
    u = (u & 0x80000000u) ? ~u : (u | 0x80000000u);
    unsigned long long key = ((unsigned long long)u << 32) | (unsigned)(~m);
    sel[u2] = (key >= thr) ? 1 : 0;
    cnt += sel[u2];
  }
  int incl = cnt;                         // inclusive wave scan
  #pragma unroll
  for (int d2 = 1; d2 < 64; d2 <<= 1){
    int v2 = __shfl_up(incl, d2);
    if ((t & 63) >= d2) incl += v2;
  }
  if ((t & 63) == 63) ws2[t >> 6] = incl;
  __syncthreads();
  int base = 0;
  const int wv2 = t >> 6;
  #pragma unroll
  for (int ww = 0; ww < 16; ww++) if (ww < wv2) base += ws2[ww];
  int pos = base + incl - cnt;            // exclusive prefix
  #pragma unroll
  for (int u2 = 0; u2 < 4; u2++){
    if (sel[u2]) tidx[(size_t)b*K_ + pos++] = 4*t + u2;
  }
}

// ---------------- Kernel 3: fused gather + Q/K/V projections via f16 MFMA ----------------
// Q is pre-scaled by QSCALE. V^T stored f16 with keys PERMUTED within each 32-token block:
//   rel key k (0..31) -> pos 8*((k&15)>>2) + 4*((k>>4)&1) + (k&3)
__global__ __launch_bounds__(512) void qkv_kernel(
    const float* __restrict__ x, const int* __restrict__ tidx,
    const unsigned short* __restrict__ wh,
    const float* __restrict__ bq, const float* __restrict__ bk, const float* __restrict__ bv,
    float* __restrict__ xsp, unsigned short* __restrict__ qbf,
    unsigned short* __restrict__ kbf, unsigned short* __restrict__ vtb)
{
  __shared__ unsigned short xsb[16][256];   // f16 bits, swizzled 16B granules
  const int t = threadIdx.x;
  const int kt = blockIdx.x, b = blockIdx.y;
  const int tok0 = kt*16;
  { // gather: thread t -> token i = t&15, granule jg = t>>4 (8 channels)
    const int i = t & 15, jg = t >> 4;
    const int n = tidx[(size_t)b*K_ + tok0 + i];
    const float* xb = x + (size_t)b*C_*N_ + n;
    float v[8];
    #pragma unroll
    for (int u = 0; u < 8; u++) v[u] = xb[(size_t)(jg*8+u)*N_];
    float* xr = xsp + ((size_t)b*K_ + tok0 + i)*C_ + jg*8;
    *(float4*)(xr)     = make_float4(v[0],v[1],v[2],v[3]);
    *(float4*)(xr + 4) = make_float4(v[4],v[5],v[6],v[7]);
    uint4 pw;
    pw.x = hpk(v[0],v[1]); pw.y = hpk(v[2],v[3]);
    pw.z = hpk(v[4],v[5]); pw.w = hpk(v[6],v[7]);
    *(uint4*)((char*)&xsb[0][0] + i*512 + ((jg ^ (i&7))*16)) = pw;
  }
  __syncthreads();

  const int lane = t & 63, w = t >> 6;
  const int g = lane >> 4, c = lane & 15;

  f32x4 acc[3][2];
  #pragma unroll
  for (int s=0;s<3;s++)
    #pragma unroll
    for (int j=0;j<2;j++) acc[s][j] = (f32x4){0.f,0.f,0.f,0.f};

  #pragma unroll 1
  for (int ks = 0; ks < 8; ks++){
    half8 Xf = *(const half8*)((const char*)&xsb[0][0] + c*512 + (((4*ks+g) ^ (c&7))*16));
    half8 Wf[3][2];
    #pragma unroll
    for (int s=0;s<3;s++)
      #pragma unroll
      for (int j=0;j<2;j++)
        Wf[s][j] = *(const half8*)(wh + (size_t)s*65536 + (32*w + 16*j + c)*C_ + ks*32 + 8*g);
    acc[0][0] = __builtin_amdgcn_mfma_f32_16x16x32_f16(Wf[0][0], Xf, acc[0][0], 0,0,0);
    acc[0][1] = __builtin_amdgcn_mfma_f32_16x16x32_f16(Wf[0][1], Xf, acc[0][1], 0,0,0);
    acc[1][0] = __builtin_amdgcn_mfma_f32_16x16x32_f16(Wf[1][0], Xf, acc[1][0], 0,0,0);
    acc[1][1] = __builtin_amdgcn_mfma_f32_16x16x32_f16(Wf[1][1], Xf, acc[1][1], 0,0,0);
    acc[2][0] = __builtin_amdgcn_mfma_f32_16x16x32_f16(Xf, Wf[2][0], acc[2][0], 0,0,0);
    acc[2][1] = __builtin_amdgcn_mfma_f32_16x16x32_f16(Xf, Wf[2][1], acc[2][1], 0,0,0);
  }

  const int bh = b*NH_ + w;   // head = wave index
  #pragma unroll
  for (int s=0;s<2;s++){
    const float* bias = s ? bk : bq;
    const float sc = s ? 1.f : QSCALE;
    unsigned short* dstb = s ? kbf : qbf;
    #pragma unroll
    for (int j=0;j<2;j++){
      f32x4 a = acc[s][j];
      float4 bb = *(const float4*)(bias + w*32 + 16*j + 4*g);
      unsigned lo = pk2((a[0]+bb.x)*sc, (a[1]+bb.y)*sc);
      unsigned hi = pk2((a[2]+bb.z)*sc, (a[3]+bb.w)*sc);
      unsigned short* dst = dstb + ((size_t)bh*K_ + tok0 + c)*HD_ + 16*j + 4*g;
      *(uint2*)dst = make_uint2(lo, hi);
    }
  }
  // V^T scatter, f16, key-permuted: lane holds tokens tok0+4g+{0..3} = rel 16*half+4g+r
  const int base32 = tok0 & ~31;
  const int half   = (tok0 >> 4) & 1;
  #pragma unroll
  for (int j=0;j<2;j++){
    f32x4 a = acc[2][j];
    const float bvv = bv[w*32 + 16*j + c];
    unsigned lo = hpk(a[0]+bvv, a[1]+bvv);
    unsigned hi = hpk(a[2]+bvv, a[3]+bvv);
    unsigned short* dst = vtb + ((size_t)bh*HD_ + 16*j + c)*K_ + base32 + 8*g + 4*half;
    *(uint2*)dst = make_uint2(lo, hi);
  }
}

// ---------------- Kernel 4: MFMA flash attention, depth-2 register pipeline ----------------
// L computed on the matrix pipe: mfma(ONES, P) gives every lane Sum_k P[k][q].
// Grid flat = h + 8*(qt + 8*b). 8 waves = (sp,qq): split-K 2-way, merge by plain addition.
__global__ __launch_bounds__(512) void attn_kernel(
    const unsigned short* __restrict__ qbf, const unsigned short* __restrict__ kbf,
    const unsigned short* __restrict__ vtb, unsigned short* __restrict__ ob)
{
  __shared__ float po[4][64][19];   // [qq][lane][ot(16) | L0 | L1]; stride 19 -> <=2-way
  const int tid = threadIdx.x;
  const int t = tid & 63, w = tid >> 6;
  const int sp = w >> 2, qq = w & 3;
  const int flat = blockIdx.x;
  const int h = flat & 7;
  const int rest = flat >> 3;      // 0..63
  const int qt = rest & 7;
  const int b = rest >> 3;         // 0..7
  const int g = t >> 4, c = t & 15;
  const int bh = b*NH_ + h;
  const int q0 = qt*128 + qq*32;   // 32 q-rows per wave

  short8 Qf0 = *(const short8*)(qbf + ((size_t)bh*K_ + q0 + c)*HD_ + g*8);
  short8 Qf1 = *(const short8*)(qbf + ((size_t)bh*K_ + q0 + 16 + c)*HD_ + g*8);

  const int kbeg = sp*512;
  const unsigned short* kp  = kbf + (size_t)bh*K_*HD_ + (size_t)(kbeg + c)*HD_ + g*8;
  const unsigned short* vp0 = vtb + ((size_t)bh*HD_ + c)*K_ + kbeg + g*8;
  const unsigned short* vp1 = vp0 + (size_t)16*K_;

  const half4 ONES = {(_Float16)1.f, (_Float16)1.f, (_Float16)1.f, (_Float16)1.f};
  f32x4 ot00 = {0.f,0.f,0.f,0.f}, ot01 = {0.f,0.f,0.f,0.f};  // qi=0: dv 0..15, 16..31
  f32x4 ot10 = {0.f,0.f,0.f,0.f}, ot11 = {0.f,0.f,0.f,0.f};  // qi=1
  f32x4 otL0 = {0.f,0.f,0.f,0.f}, otL1 = {0.f,0.f,0.f,0.f};  // L accumulators

#define ATTN_STEP(K0c,K1c,V0c,V1c) do {                                           \
    f32x4 z = {0.f,0.f,0.f,0.f};                                                  \
    __builtin_amdgcn_s_setprio(1);                                                \
    f32x4 s00 = __builtin_amdgcn_mfma_f32_16x16x32_bf16(K0c, Qf0, z, 0, 0, 0);    \
    f32x4 s01 = __builtin_amdgcn_mfma_f32_16x16x32_bf16(K1c, Qf0, z, 0, 0, 0);    \
    f32x4 s10 = __builtin_amdgcn_mfma_f32_16x16x32_bf16(K0c, Qf1, z, 0, 0, 0);    \
    f32x4 s11 = __builtin_amdgcn_mfma_f32_16x16x32_bf16(K1c, Qf1, z, 0, 0, 0);    \
    __builtin_amdgcn_s_setprio(0);                                                \
    float p00[4], p01[4], p10[4], p11[4];                                         \
    _Pragma("unroll")                                                             \
    for (int r=0;r<4;r++){                                                        \
      p00[r] = EXPX(s00[r]); p01[r] = EXPX(s01[r]);                               \
      p10[r] = EXPX(s10[r]); p11[r] = EXPX(s11[r]);                               \
    }                                                                             \
    half4 P00 = pk4rtz(p00[0], p00[1], p00[2], p00[3]);                           \
    half4 P01 = pk4rtz(p01[0], p01[1], p01[2], p01[3]);                           \
    half4 P10 = pk4rtz(p10[0], p10[1], p10[2], p10[3]);                           \
    half4 P11 = pk4rtz(p11[0], p11[1], p11[2], p11[3]);                           \
    half4 A0lo = __builtin_shufflevector(V0c, V0c, 0, 1, 2, 3);                   \
    half4 A0hi = __builtin_shufflevector(V0c, V0c, 4, 5, 6, 7);                   \
    half4 A1lo = __builtin_shufflevector(V1c, V1c, 0, 1, 2, 3);                   \
    half4 A1hi = __builtin_shufflevector(V1c, V1c, 4, 5, 6, 7);                   \
    __builtin_amdgcn_s_setprio(1);                                                \
    ot00 = __builtin_amdgcn_mfma_f32_16x16x16f16(A0lo, P00, ot00, 0, 0, 0);       \
    ot00 = __builtin_amdgcn_mfma_f32_16x16x16f16(A0hi, P01, ot00, 0, 0, 0);       \
    ot01 = __builtin_amdgcn_mfma_f32_16x16x16f16(A1lo, P00, ot01, 0, 0, 0);       \
    ot01 = __builtin_amdgcn_mfma_f32_16x16x16f16(A1hi, P01, ot01, 0, 0, 0);       \
    ot10 = __builtin_amdgcn_mfma_f32_16x16x16f16(A0lo, P10, ot10, 0, 0, 0);       \
    ot10 = __builtin_amdgcn_mfma_f32_16x16x16f16(A0hi, P11, ot10, 0, 0, 0);       \
    ot11 = __builtin_amdgcn_mfma_f32_16x16x16f16(A1lo, P10, ot11, 0, 0, 0);       \
    ot11 = __builtin_amdgcn_mfma_f32_16x16x16f16(A1hi, P11, ot11, 0, 0, 0);       \
    otL0 = __builtin_amdgcn_mfma_f32_16x16x16f16(ONES, P00, otL0, 0, 0, 0);       \
    otL0 = __builtin_amdgcn_mfma_f32_16x16x16f16(ONES, P01, otL0, 0, 0, 0);       \
    otL1 = __builtin_amdgcn_mfma_f32_16x16x16f16(ONES, P10, otL1, 0, 0, 0);       \
    otL1 = __builtin_amdgcn_mfma_f32_16x16x16f16(ONES, P11, otL1, 0, 0, 0);       \
    __builtin_amdgcn_s_setprio(0);                                                \
  } while(0)

  // depth-2 register pipeline; prefetches past the region land in allocated workspace
  short8 K0a = *(const short8*)(kp);
  short8 K1a = *(const short8*)(kp + 16*HD_);
  half8  V0a = *(const half8*)(vp0);
  half8  V1a = *(const half8*)(vp1);
  kp += 32*HD_; vp0 += 32; vp1 += 32;
  short8 K0b = *(const short8*)(kp);
  short8 K1b = *(const short8*)(kp + 16*HD_);
  half8  V0b = *(const half8*)(vp0);
  half8  V1b = *(const half8*)(vp1);

  for (int it = 0; it < 16; it += 2){
    kp += 32*HD_; vp0 += 32; vp1 += 32;
    short8 K0n = *(const short8*)(kp);
    short8 K1n = *(const short8*)(kp + 16*HD_);
    half8  V0n = *(const half8*)(vp0);
    half8  V1n = *(const half8*)(vp1);
    ATTN_STEP(K0a, K1a, V0a, V1a);
    K0a = K0n; K1a = K1n; V0a = V0n; V1a = V1n;
    kp += 32*HD_; vp0 += 32; vp1 += 32;
    short8 K0m = *(const short8*)(kp);
    short8 K1m = *(const short8*)(kp + 16*HD_);
    half8  V0m = *(const half8*)(vp0);
    half8  V1m = *(const half8*)(vp1);
    ATTN_STEP(K0b, K1b, V0b, V1b);
    K0b = K0m; K1b = K1m; V0b = V0m; V1b = V1m;
  }
#undef ATTN_STEP

  if (sp == 1){
    float* d = po[qq][t];
    d[0]=ot00[0]; d[1]=ot00[1]; d[2]=ot00[2];  d[3]=ot00[3];
    d[4]=ot01[0]; d[5]=ot01[1]; d[6]=ot01[2];  d[7]=ot01[3];
    d[8]=ot10[0]; d[9]=ot10[1]; d[10]=ot10[2]; d[11]=ot10[3];
    d[12]=ot11[0];d[13]=ot11[1];d[14]=ot11[2]; d[15]=ot11[3];
    d[16]=otL0[0]; d[17]=otL1[0];
  }
  __syncthreads();
  if (sp == 0){
    const float* d = po[qq][t];
    ot00[0]+=d[0]; ot00[1]+=d[1]; ot00[2]+=d[2];  ot00[3]+=d[3];
    ot01[0]+=d[4]; ot01[1]+=d[5]; ot01[2]+=d[6];  ot01[3]+=d[7];
    ot10[0]+=d[8]; ot10[1]+=d[9]; ot10[2]+=d[10]; ot10[3]+=d[11];
    ot11[0]+=d[12];ot11[1]+=d[13];ot11[2]+=d[14]; ot11[3]+=d[15];
    const float L0 = otL0[0] + d[16];
    const float L1 = otL1[0] + d[17];
    const float i0 = 1.f / L0, i1 = 1.f / L1;
    unsigned short* o0 = ob + ((size_t)b*K_ + q0 + c)*C_ + h*HD_;
    unsigned short* o1 = ob + ((size_t)b*K_ + q0 + 16 + c)*C_ + h*HD_;
    *(uint2*)(o0 + 4*g)      = make_uint2(hpk(ot00[0]*i0, ot00[1]*i0), hpk(ot00[2]*i0, ot00[3]*i0));
    *(uint2*)(o0 + 16 + 4*g) = make_uint2(hpk(ot01[0]*i0, ot01[1]*i0), hpk(ot01[2]*i0, ot01[3]*i0));
    *(uint2*)(o1 + 4*g)      = make_uint2(hpk(ot10[0]*i1, ot10[1]*i1), hpk(ot10[2]*i1, ot10[3]*i1));
    *(uint2*)(o1 + 16 + 4*g) = make_uint2(hpk(ot11[0]*i1, ot11[1]*i1), hpk(ot11[2]*i1, ot11[3]*i1));
  }
}

// ---------------- Kernel 5: out-proj (f16 MFMA) + residual + LayerNorm + scatter ----------------
// 32-token tiles -> grid (32,8) = 256 blocks (one per CU).
__global__ __launch_bounds__(512) void out_kernel(
    const unsigned short* __restrict__ ob, const float* __restrict__ xsp,
    const int* __restrict__ tidx, const unsigned short* __restrict__ woh, const float* __restrict__ bo,
    const float* __restrict__ lng, const float* __restrict__ lnb,
    float* __restrict__ out)
{
  __shared__ float red1[8][32], red2[8][32];
  __shared__ float mus[32], rss[32];
  __shared__ int nn[32];
  const int t = threadIdx.x;
  const int kt = blockIdx.x, b = blockIdx.y;
  const int tok0 = kt*32;
  const int lane = t & 63, w = t >> 6;
  const int g = lane >> 4, c = lane & 15;

  if (t < 32) nn[t] = tidx[(size_t)b*K_ + tok0 + t];

  f32x4 acc[2][2];
  #pragma unroll
  for (int j=0;j<2;j++)
    #pragma unroll
    for (int tt=0;tt<2;tt++) acc[j][tt] = (f32x4){0.f,0.f,0.f,0.f};

  const unsigned short* ob0 = ob + ((size_t)b*K_ + tok0)*C_;
  const unsigned short* wr0 = woh + (32*w + c)*C_;

  #pragma unroll 1
  for (int ks = 0; ks < 8; ks++){
    half8 Wf0 = *(const half8*)(wr0 + ks*32 + 8*g);
    half8 Wf1 = *(const half8*)(wr0 + 16*C_ + ks*32 + 8*g);
    #pragma unroll
    for (int tt=0;tt<2;tt++){
      half8 Of = *(const half8*)(ob0 + (size_t)(16*tt + c)*C_ + ks*32 + 8*g);
      acc[0][tt] = __builtin_amdgcn_mfma_f32_16x16x32_f16(Wf0, Of, acc[0][tt], 0,0,0);
      acc[1][tt] = __builtin_amdgcn_mfma_f32_16x16x32_f16(Wf1, Of, acc[1][tt], 0,0,0);
    }
  }

  // bias + residual (fp32)
  float4 bb[2];
  #pragma unroll
  for (int j=0;j<2;j++) bb[j] = *(const float4*)(bo + 32*w + 16*j + 4*g);
  #pragma unroll
  for (int tt=0;tt<2;tt++){
    const float* xr = xsp + ((size_t)b*K_ + tok0 + 16*tt + c)*C_ + 32*w + 4*g;
    #pragma unroll
    for (int j=0;j<2;j++){
      float4 xv = *(const float4*)(xr + 16*j);
      acc[j][tt][0] += bb[j].x + xv.x;
      acc[j][tt][1] += bb[j].y + xv.y;
      acc[j][tt][2] += bb[j].z + xv.z;
      acc[j][tt][3] += bb[j].w + xv.w;
    }
  }

  // LN partials: per token sum over this wave's 32 oc; g-groups share the token
  #pragma unroll
  for (int tt=0;tt<2;tt++){
    float s1 = 0.f, s2 = 0.f;
    #pragma unroll
    for (int j=0;j<2;j++)
      #pragma unroll
      for (int r=0;r<4;r++){ float y = acc[j][tt][r]; s1 += y; s2 += y*y; }
    s1 += __shfl_xor(s1, 16); s2 += __shfl_xor(s2, 16);
    s1 += __shfl_xor(s1, 32); s2 += __shfl_xor(s2, 32);
    if (g == 0){ red1[w][16*tt + c] = s1; red2[w][16*tt + c] = s2; }
  }
  __syncthreads();
  if (t < 32){
    float a = 0.f, q2 = 0.f;
    #pragma unroll
    for (int ww=0;ww<8;ww++){ a += red1[ww][t]; q2 += red2[ww][t]; }
    float mu = a*(1.f/256.f);
    float var = q2*(1.f/256.f) - mu*mu;
    mus[t] = mu;
    rss[t] = rsqrtf(var + 1e-5f);
  }
  __syncthreads();

  // scale/shift + scatter
  float4 gv[2], bv2[2];
  #pragma unroll
  for (int j=0;j<2;j++){
    gv[j]  = *(const float4*)(lng + 32*w + 16*j + 4*g);
    bv2[j] = *(const float4*)(lnb + 32*w + 16*j + 4*g);
  }
  float* outb = out + (size_t)b*C_*N_;
  #pragma unroll
  for (int tt=0;tt<2;tt++){
    const int tok = 16*tt + c;
    const float mu = mus[tok], rs = rss[tok];
    const int n = nn[tok];
    #pragma unroll
    for (int j=0;j<2;j++){
      const int oc0 = 32*w + 16*j + 4*g;
      const float* gvp = (const float*)&gv[j];
      const float* bvp = (const float*)&bv2[j];
      #pragma unroll
      for (int r=0;r<4;r++)
        outb[(size_t)(oc0 + r)*N_ + n] = (acc[j][tt][r]-mu)*rs*gvp[r] + bvp[r];
    }
  }
}

extern "C" void kernel_launch(void* const* d_in, const int* in_sizes, int n_in,
                              void* d_out, int out_size, void* d_ws, size_t ws_size,
                              hipStream_t stream)
{
  const float* x    = (const float*)d_in[0];
  const float* bmap = (const float*)d_in[1];
  const float* w1   = (const float*)d_in[2];
  const float* b1   = (const float*)d_in[3];
  const float* w2   = (const float*)d_in[4];
  const float* b2   = (const float*)d_in[5];
  const float* wq   = (const float*)d_in[6];
  const float* bq   = (const float*)d_in[7];
  const float* wk   = (const float*)d_in[8];
  const float* bk   = (const float*)d_in[9];
  const float* wv   = (const float*)d_in[10];
  const float* bv   = (const float*)d_in[11];
  const float* wo   = (const float*)d_in[12];
  const float* bo   = (const float*)d_in[13];
  const float* lng  = (const float*)d_in[14];
  const float* lnb  = (const float*)d_in[15];

  float* out = (float*)d_out;
  float* imp_out = out + (size_t)B_*C_*N_;   // importance is output #2, concatenated

  char* wsb = (char*)d_ws;
  int*   tidx = (int*)wsb;                                // 64 KB slot
  float* xsp  = (float*)(wsb + 65536);                    // [B,K,C] fp32, 8 MB
  unsigned short* ob16 = (unsigned short*)(xsp + (size_t)B_*K_*C_); // [B,K,C] f16, 4 MB (8 MB slot)
  unsigned short* qbf = ob16 + 2*(size_t)B_*K_*C_;        // [B,H,K,32] bf16, 4 MB
  unsigned short* kbf = qbf + (size_t)B_*NH_*K_*HD_;      // [B,H,K,32] bf16, 4 MB
  unsigned short* vtb = kbf + (size_t)B_*NH_*K_*HD_;      // [B,H,32,K] f16 key-permuted, 4 MB
  unsigned short* wh  = vtb + (size_t)B_*NH_*K_*HD_;      // [4][256][256] f16, 512 KB

  w2h_kernel <<<dim3(32, 4),    dim3(256),  0, stream>>>(wq, wk, wv, wo, wh);
  imp_kernel <<<dim3(512),      dim3(256),  0, stream>>>(x, bmap, w1, b1, w2, b2, imp_out, out);
  topk_kernel<<<dim3(8),        dim3(1024), 0, stream>>>(imp_out, tidx);
  qkv_kernel <<<dim3(64, 8),    dim3(512),  0, stream>>>(x, tidx, wh, bq, bk, bv, xsp, qbf, kbf, vtb);
  attn_kernel<<<dim3(512),      dim3(512),  0, stream>>>(qbf, kbf, vtb, ob16);
  out_kernel <<<dim3(32, 8),    dim3(512),  0, stream>>>(ob16, xsp, tidx, wh + 3*65536, bo, lng, lnb, out);
}